// Round 11
// baseline (5732.278 us; speedup 1.0000x reference)
//
#include <hip/hip_runtime.h>

typedef unsigned short u16;
typedef unsigned int u32;
typedef unsigned long long u64;
typedef __attribute__((ext_vector_type(8))) short short8v;
typedef __attribute__((ext_vector_type(4))) short short4v;
typedef __attribute__((ext_vector_type(8))) __bf16 bf16x8;
typedef __attribute__((ext_vector_type(4))) float f32x4;

#define AS1 __attribute__((address_space(1)))
#define AS3 __attribute__((address_space(3)))

// ---------- helpers ----------
__device__ __forceinline__ u16 f2bf(float f) {
  unsigned u = __float_as_uint(f);
  u += 0x7fffu + ((u >> 16) & 1u);   // round-to-nearest-even
  return (u16)(u >> 16);
}
__device__ __forceinline__ float bf2f(u16 h) {
  return __uint_as_float(((unsigned)h) << 16);
}
__device__ __forceinline__ void gload_lds16(const void* g, void* l) {
  __builtin_amdgcn_global_load_lds((const AS1 void*)g, (AS3 void*)l, 16, 0, 0);
}
__device__ __forceinline__ bf16x8 ld8(const u16* p) {
  return __builtin_bit_cast(bf16x8, *reinterpret_cast<const short8v*>(p));
}
__device__ __forceinline__ float sigf(float x) { return 1.0f / (1.0f + __expf(-x)); }
__device__ __forceinline__ float tanhfast(float x) {
  float e = __expf(2.0f * x);
  return 1.0f - 2.0f / (e + 1.0f);
}

// ---------- setup kernels ----------
__global__ __launch_bounds__(256) void k_conv_x(const float* __restrict__ x,
                                                u16* __restrict__ xh) {
  int i = blockIdx.x * 256 + threadIdx.x;
  float4 v = reinterpret_cast<const float4*>(x)[i];
  ushort4 o;
  o.x = f2bf(v.x); o.y = f2bf(v.y); o.z = f2bf(v.z); o.w = f2bf(v.w);
  reinterpret_cast<ushort4*>(xh)[i] = o;
}

// gate-interleaved packing: n' = d*2048 + 4j + g, src row = g*512 + j
__global__ __launch_bounds__(256) void k_pack_w(
    const float* __restrict__ Wx_f, const float* __restrict__ Wh_f,
    const float* __restrict__ bx_f, const float* __restrict__ bh_f,
    const float* __restrict__ Wx_b, const float* __restrict__ Wh_b,
    const float* __restrict__ bx_b, const float* __restrict__ bh_b,
    u16* __restrict__ wall, u16* __restrict__ whp, float* __restrict__ bias) {
  int i = blockIdx.x * 256 + threadIdx.x;
  int np = i >> 7;
  int k4 = i & 127;
  int d  = np >> 11;
  int p  = np & 2047;
  int src = (p & 3) * 512 + (p >> 2);
  const float* wx = d ? Wx_b : Wx_f;
  const float* wh = d ? Wh_b : Wh_f;
  float4 vx = reinterpret_cast<const float4*>(wx + (size_t)src * 512)[k4];
  float4 vh = reinterpret_cast<const float4*>(wh + (size_t)src * 512)[k4];
  ushort4 ox, oh;
  ox.x = f2bf(vx.x); ox.y = f2bf(vx.y); ox.z = f2bf(vx.z); ox.w = f2bf(vx.w);
  oh.x = f2bf(vh.x); oh.y = f2bf(vh.y); oh.z = f2bf(vh.z); oh.w = f2bf(vh.w);
  reinterpret_cast<ushort4*>(wall + (size_t)np * 512)[k4] = ox;
  reinterpret_cast<ushort4*>(whp  + (size_t)np * 512)[k4] = oh;
  if (k4 == 0) bias[np] = d ? (bx_b[src] + bh_b[src]) : (bx_f[src] + bh_f[src]);
}

// ---------- phase 1: xg = xh @ wall^T + bias ----------
template <bool XGBF16>
__global__ __launch_bounds__(256) void k_gemm_xg(
    const u16* __restrict__ A, const u16* __restrict__ Bw,
    const float* __restrict__ bias,
    float* __restrict__ Cf, u16* __restrict__ Ch) {
  __shared__ __align__(16) u16 lA[128 * 32];
  __shared__ __align__(16) u16 lB[128 * 32];
  const int tid  = threadIdx.x;
  const int lane = tid & 63;
  const int w    = tid >> 6;
  const int wr   = w >> 1, wc = w & 1;
  const size_t brow = (size_t)blockIdx.y * 128;
  const int    bcol = blockIdx.x * 128;

  f32x4 acc[4][4] = {};

  for (int kk = 0; kk < 16; ++kk) {
    const int k0 = kk * 32;
    __syncthreads();
#pragma unroll
    for (int q = 0; q < 2; ++q) {
      int idx = q * 256 + tid;
      int row = idx >> 2, c = idx & 3;
      gload_lds16(A  + (brow + row) * 512 + k0 + c * 8, &lA[idx * 8]);
      gload_lds16(Bw + (size_t)(bcol + row) * 512 + k0 + c * 8, &lB[idx * 8]);
    }
    __syncthreads();

    bf16x8 af[4], bfr[4];
#pragma unroll
    for (int m = 0; m < 4; ++m) {
      int row = wr * 64 + m * 16 + (lane & 15);
      af[m] = ld8(&lA[row * 32 + (lane >> 4) * 8]);
    }
#pragma unroll
    for (int n = 0; n < 4; ++n) {
      int row = wc * 64 + n * 16 + (lane & 15);
      bfr[n] = ld8(&lB[row * 32 + (lane >> 4) * 8]);
    }
#pragma unroll
    for (int m = 0; m < 4; ++m)
#pragma unroll
      for (int n = 0; n < 4; ++n)
        acc[m][n] = __builtin_amdgcn_mfma_f32_16x16x32_bf16(af[m], bfr[n], acc[m][n], 0, 0, 0);
  }

#pragma unroll
  for (int m = 0; m < 4; ++m) {
#pragma unroll
    for (int n = 0; n < 4; ++n) {
      int col = bcol + wc * 64 + n * 16 + (lane & 15);
      float bb = bias[col];
#pragma unroll
      for (int r = 0; r < 4; ++r) {
        size_t row = brow + wr * 64 + m * 16 + (lane >> 4) * 4 + r;
        float v = acc[m][n][r] + bb;
        if (XGBF16) Ch[row * 4096 + col] = f2bf(v);
        else        Cf[row * 4096 + col] = v;
      }
    }
  }
}

// ---------- phase 2: persistent recurrence, 2-dir interleave ----------
// 32 blocks x 512 threads. Each block owns 64 gate-cols (16 hidden units) of
// BOTH directions and alternates d0/d1 half-rounds; the flag-detect + h-load
// latency of one direction hides under the other's compute.
// h layout (block-major, dense publish): hbuf[pp][dir][blk][b 0..31][8 u32].
// 8 waves = (kh kk-half, nt n-tile); wf = 8 frags/dir/wave (64 VGPR both).
// Per-thread h load: 8 u64 from ONE producer blk (128B-contiguous lane
// groups); spin on that blk's flag; block sync joins coverage of all 32.
template <bool XGBF16>
__global__ __launch_bounds__(512, 1) void k_rnn(
    const u16* __restrict__ whp,
    const float* __restrict__ xgf, const u16* __restrict__ xgh,
    u32* __restrict__ hbuf, u32* __restrict__ flags,
    float* __restrict__ out, float* __restrict__ fh, float* __restrict__ fc) {
  const int tid = threadIdx.x;
  const int l   = tid & 63;
  const int W   = tid >> 6;             // wave 0..7
  const int bid = (int)blockIdx.x;      // 0..31
  const int r0  = l & 15;
  const int hi  = l >> 4;
  const int kh  = W >> 2;               // kk half (0: kk 0-7, 1: kk 8-15)
  const int nt  = W & 3;                // n-tile (16 cols each)
  const int blkld = W * 4 + hi;         // producer blk of my staged h slice
  const int lof = l & 15;
  const int swz = r0 & 7;
  const int b   = tid >> 4;             // gate cell: batch row 0..31
  const int j   = tid & 15;             // gate cell: local hidden idx 0..15

  __shared__ __align__(16) u16 hlds[32 * 512];        // 32 KB staged h
  __shared__ __align__(16) float gbufH[2][32][72];    // kk-half partial sums

  // ---- Wh fragments (both dirs), 8 frags each ----
  bf16x8 wf0[8], wf1[8];
#pragma unroll
  for (int k = 0; k < 8; ++k) {
    size_t rowoff = (size_t)(bid * 64 + nt * 16 + r0) * 512 + (kh * 8 + k) * 32 + hi * 8;
    wf0[k] = ld8(whp + rowoff);
    wf1[k] = ld8(whp + (size_t)2048 * 512 + rowoff);
  }

  float cst0 = 0.f, cst1 = 0.f;
  const int FSTR = 16;                                 // 64 B between flags

  for (int t = 0; t < 1024; ++t) {
    const int sd0 = t, sd1 = 1023 - t;

    // ---- xg prefetch for both dirs (issued before any spin) ----
    float xga[4], xgb[4];
    {
      size_t xo0 = ((size_t)(b * 1024 + sd0)) * 4096 + (size_t)(bid * 64 + j * 4);
      size_t xo1 = ((size_t)(b * 1024 + sd1)) * 4096 + (size_t)(2048 + bid * 64 + j * 4);
      if (XGBF16) {
        short4v v0 = *reinterpret_cast<const short4v*>(xgh + xo0);
        short4v v1 = *reinterpret_cast<const short4v*>(xgh + xo1);
        xga[0] = bf2f((u16)v0[0]); xga[1] = bf2f((u16)v0[1]);
        xga[2] = bf2f((u16)v0[2]); xga[3] = bf2f((u16)v0[3]);
        xgb[0] = bf2f((u16)v1[0]); xgb[1] = bf2f((u16)v1[1]);
        xgb[2] = bf2f((u16)v1[2]); xgb[3] = bf2f((u16)v1[3]);
      } else {
        f32x4 v0 = *reinterpret_cast<const f32x4*>(xgf + xo0);
        f32x4 v1 = *reinterpret_cast<const f32x4*>(xgf + xo1);
        xga[0] = v0[0]; xga[1] = v0[1]; xga[2] = v0[2]; xga[3] = v0[3];
        xgb[0] = v1[0]; xgb[1] = v1[1]; xgb[2] = v1[2]; xgb[3] = v1[3];
      }
    }

    // ================= half-round macro body (d as literal) =================
#define HALF_STEP(D, SD, WF, XG, CST)                                          \
    {                                                                          \
      const u32* spf = flags + (size_t)(D * 32 + blkld) * FSTR;                \
      u32* flg       = flags + (size_t)(D * 32 + bid) * FSTR;                  \
      if (t > 0) {                                                             \
        while (__hip_atomic_load(spf, __ATOMIC_RELAXED,                        \
                                 __HIP_MEMORY_SCOPE_AGENT) < (u32)t)           \
          __builtin_amdgcn_s_sleep(1);                                         \
        asm volatile("" ::: "memory");                                         \
      }                                                                        \
      /* load 8 u64 from producer blkld (128B-contiguous lane groups) */       \
      const u64* hb = (const u64*)hbuf + ((size_t)(t & 1) * 2 + D) * 4096;     \
      u64 hv[8];                                                               \
      _Pragma("unroll")                                                        \
      for (int p = 0; p < 8; ++p)                                              \
        hv[p] = __hip_atomic_load(hb + blkld * 128 + p * 16 + lof,             \
                                  __ATOMIC_RELAXED, __HIP_MEMORY_SCOPE_AGENT); \
      {                                                                        \
        char* hby = (char*)hlds;                                               \
        _Pragma("unroll")                                                      \
        for (int p = 0; p < 8; ++p) {                                          \
          int bb = p * 4 + (lof >> 2);                                         \
          int c  = blkld * 4 + (lof & 3);                                      \
          *(u64*)(hby + bb * 1024 + (((c >> 1) ^ (bb & 7)) << 4) +             \
                  ((c & 1) << 3)) = hv[p];                                     \
        }                                                                      \
      }                                                                        \
      __syncthreads();                                                         \
      f32x4 acc[2] = {};                                                       \
      {                                                                        \
        const char* hbc = (const char*)hlds;                                   \
        _Pragma("unroll")                                                      \
        for (int k = 0; k < 8; ++k) {                                          \
          int kk = kh * 8 + k;                                                 \
          int u0 = (((kk * 4 + hi) ^ swz) << 4);                               \
          bf16x8 a0 = *(const bf16x8*)(hbc + r0 * 1024 + u0);                  \
          bf16x8 a1 = *(const bf16x8*)(hbc + (16 + r0) * 1024 + u0);           \
          acc[0] = __builtin_amdgcn_mfma_f32_16x16x32_bf16(a0, WF[k], acc[0], 0, 0, 0); \
          acc[1] = __builtin_amdgcn_mfma_f32_16x16x32_bf16(a1, WF[k], acc[1], 0, 0, 0); \
        }                                                                      \
      }                                                                        \
      _Pragma("unroll")                                                        \
      for (int m = 0; m < 2; ++m)                                              \
        _Pragma("unroll")                                                      \
        for (int r = 0; r < 4; ++r)                                            \
          gbufH[kh][m * 16 + hi * 4 + r][nt * 16 + r0] = acc[m][r];            \
      __syncthreads();                                                         \
      f32x4 ga = *reinterpret_cast<const f32x4*>(&gbufH[0][b][j * 4]);         \
      f32x4 gbv = *reinterpret_cast<const f32x4*>(&gbufH[1][b][j * 4]);        \
      float gi = ga[0] + gbv[0] + XG[0];                                       \
      float gf = ga[1] + gbv[1] + XG[1];                                       \
      float go = ga[2] + gbv[2] + XG[2];                                       \
      float gc = ga[3] + gbv[3] + XG[3];                                       \
      float cn = sigf(gf) * CST + sigf(gi) * tanhfast(gc);                     \
      float hn = sigf(go) * tanhfast(cn);                                      \
      CST = cn;                                                                \
      float hp = __shfl_xor(hn, 1);                                            \
      if (!(j & 1)) {                                                          \
        u32 pk = (u32)f2bf(hn) | ((u32)f2bf(hp) << 16);                        \
        u32* hd = hbuf + ((size_t)((t + 1) & 1) * 2 + D) * 8192 +              \
                  bid * 256 + b * 8 + (j >> 1);                                \
        __hip_atomic_store(hd, pk, __ATOMIC_RELAXED, __HIP_MEMORY_SCOPE_AGENT);\
      }                                                                        \
      asm volatile("s_waitcnt vmcnt(0)" ::: "memory");                         \
      __syncthreads();                                                         \
      if (tid == 0)                                                            \
        __hip_atomic_store(flg, (u32)(t + 1), __ATOMIC_RELAXED,                \
                           __HIP_MEMORY_SCOPE_AGENT);                          \
      __builtin_nontemporal_store(hn,                                          \
          out + ((size_t)(b * 1024 + SD)) * 1024 + D * 512 + bid * 16 + j);    \
      if (t == 1023) {                                                         \
        int fo = b * 1024 + D * 512 + bid * 16 + j;                            \
        fh[fo] = hn;                                                           \
        fc[fo] = cn;                                                           \
      }                                                                        \
    }
    // =======================================================================

    HALF_STEP(0, sd0, wf0, xga, cst0)
    HALF_STEP(1, sd1, wf1, xgb, cst1)
#undef HALF_STEP
  }
}

// ---------- host ----------
extern "C" void kernel_launch(void* const* d_in, const int* in_sizes, int n_in,
                              void* d_out, int out_size, void* d_ws, size_t ws_size,
                              hipStream_t stream) {
  (void)in_sizes; (void)n_in; (void)out_size;
  const float* x    = (const float*)d_in[0];
  const float* Wx_f = (const float*)d_in[1];
  const float* Wh_f = (const float*)d_in[2];
  const float* bx_f = (const float*)d_in[3];
  const float* bh_f = (const float*)d_in[4];
  const float* Wx_b = (const float*)d_in[5];
  const float* Wh_b = (const float*)d_in[6];
  const float* bx_b = (const float*)d_in[7];
  const float* bh_b = (const float*)d_in[8];

  char* ws = (char*)d_ws;
  const size_t XG_F32 = (size_t)32768 * 4096 * 4;   // 512 MB
  const size_t XG_BF  = (size_t)32768 * 4096 * 2;   // 256 MB
  const size_t REST   = 33554432 + 4194304 + 4194304 + 16384 + 131072 + 4096;
  const bool xg_bf16 = (ws_size < XG_F32 + REST);

  size_t off = xg_bf16 ? XG_BF : XG_F32;
  float* xg_f = (float*)ws;
  u16*   xg_h = (u16*)ws;
  u16*   xh   = (u16*)(ws + off);  off += 33554432;   // x as bf16
  u16*   wall = (u16*)(ws + off);  off += 4194304;    // packed Wx (both dirs)
  u16*   whp  = (u16*)(ws + off);  off += 4194304;    // packed Wh (both dirs)
  float* bias = (float*)(ws + off); off += 16384;     // bx+bh packed
  u32*   hbuf = (u32*)(ws + off);  off += 131072;     // [2pp][2dir][32blk][32b][8u32]
  u32*   flags = (u32*)(ws + off); off += 4096;       // 2 dir x 32 blk, 64B apart

  float* out = (float*)d_out;
  float* fh  = out + (size_t)33554432;
  float* fc  = fh + 32768;

  hipError_t e = hipMemsetAsync(hbuf, 0, 131072 + 4096, stream); // h + flags
  (void)e;
  k_conv_x<<<16384, 256, 0, stream>>>(x, xh);
  k_pack_w<<<2048, 256, 0, stream>>>(Wx_f, Wh_f, bx_f, bh_f,
                                     Wx_b, Wh_b, bx_b, bh_b, wall, whp, bias);
  if (xg_bf16) {
    k_gemm_xg<true><<<dim3(32, 256), 256, 0, stream>>>(xh, wall, bias, nullptr, xg_h);
    k_rnn<true><<<32, 512, 0, stream>>>(whp, nullptr, xg_h, hbuf, flags, out, fh, fc);
  } else {
    k_gemm_xg<false><<<dim3(32, 256), 256, 0, stream>>>(xh, wall, bias, xg_f, nullptr);
    k_rnn<false><<<32, 512, 0, stream>>>(whp, xg_f, nullptr, hbuf, flags, out, fh, fc);
  }
}

// Round 12
// 4293.133 us; speedup vs baseline: 1.3352x; 1.3352x over previous
//
#include <hip/hip_runtime.h>

typedef unsigned short u16;
typedef unsigned int u32;
typedef unsigned long long u64;
typedef __attribute__((ext_vector_type(8))) short short8v;
typedef __attribute__((ext_vector_type(8))) __bf16 bf16x8;
typedef __attribute__((ext_vector_type(4))) float f32x4;
typedef __attribute__((ext_vector_type(2))) float f32x2;

#define AS1 __attribute__((address_space(1)))
#define AS3 __attribute__((address_space(3)))

// ---------- helpers ----------
__device__ __forceinline__ u16 f2bf(float f) {
  unsigned u = __float_as_uint(f);
  u += 0x7fffu + ((u >> 16) & 1u);   // round-to-nearest-even
  return (u16)(u >> 16);
}
__device__ __forceinline__ float bf2f(u16 h) {
  return __uint_as_float(((unsigned)h) << 16);
}
__device__ __forceinline__ void gload_lds16(const void* g, void* l) {
  __builtin_amdgcn_global_load_lds((const AS1 void*)g, (AS3 void*)l, 16, 0, 0);
}
__device__ __forceinline__ bf16x8 ld8(const u16* p) {
  return __builtin_bit_cast(bf16x8, *reinterpret_cast<const short8v*>(p));
}
__device__ __forceinline__ float sigf(float x) { return 1.0f / (1.0f + __expf(-x)); }
__device__ __forceinline__ float tanhfast(float x) {
  float e = __expf(2.0f * x);
  return 1.0f - 2.0f / (e + 1.0f);
}

// ---------- setup kernels ----------
__global__ __launch_bounds__(256) void k_conv_x(const float* __restrict__ x,
                                                u16* __restrict__ xh) {
  int i = blockIdx.x * 256 + threadIdx.x;
  float4 v = reinterpret_cast<const float4*>(x)[i];
  ushort4 o;
  o.x = f2bf(v.x); o.y = f2bf(v.y); o.z = f2bf(v.z); o.w = f2bf(v.w);
  reinterpret_cast<ushort4*>(xh)[i] = o;
}

// gate-interleaved packing: n' = d*2048 + 4j + g, src row = g*512 + j
__global__ __launch_bounds__(256) void k_pack_w(
    const float* __restrict__ Wx_f, const float* __restrict__ Wh_f,
    const float* __restrict__ bx_f, const float* __restrict__ bh_f,
    const float* __restrict__ Wx_b, const float* __restrict__ Wh_b,
    const float* __restrict__ bx_b, const float* __restrict__ bh_b,
    u16* __restrict__ wall, u16* __restrict__ whp, float* __restrict__ bias) {
  int i = blockIdx.x * 256 + threadIdx.x;
  int np = i >> 7;
  int k4 = i & 127;
  int d  = np >> 11;
  int p  = np & 2047;
  int src = (p & 3) * 512 + (p >> 2);
  const float* wx = d ? Wx_b : Wx_f;
  const float* wh = d ? Wh_b : Wh_f;
  float4 vx = reinterpret_cast<const float4*>(wx + (size_t)src * 512)[k4];
  float4 vh = reinterpret_cast<const float4*>(wh + (size_t)src * 512)[k4];
  ushort4 ox, oh;
  ox.x = f2bf(vx.x); ox.y = f2bf(vx.y); ox.z = f2bf(vx.z); ox.w = f2bf(vx.w);
  oh.x = f2bf(vh.x); oh.y = f2bf(vh.y); oh.z = f2bf(vh.z); oh.w = f2bf(vh.w);
  reinterpret_cast<ushort4*>(wall + (size_t)np * 512)[k4] = ox;
  reinterpret_cast<ushort4*>(whp  + (size_t)np * 512)[k4] = oh;
  if (k4 == 0) bias[np] = d ? (bx_b[src] + bh_b[src]) : (bx_f[src] + bh_f[src]);
}

// ---------- phase 1: xg = xh @ wall^T + bias ----------
template <bool XGBF16>
__global__ __launch_bounds__(256) void k_gemm_xg(
    const u16* __restrict__ A, const u16* __restrict__ Bw,
    const float* __restrict__ bias,
    float* __restrict__ Cf, u16* __restrict__ Ch) {
  __shared__ __align__(16) u16 lA[128 * 32];
  __shared__ __align__(16) u16 lB[128 * 32];
  const int tid  = threadIdx.x;
  const int lane = tid & 63;
  const int w    = tid >> 6;
  const int wr   = w >> 1, wc = w & 1;
  const size_t brow = (size_t)blockIdx.y * 128;
  const int    bcol = blockIdx.x * 128;

  f32x4 acc[4][4] = {};

  for (int kk = 0; kk < 16; ++kk) {
    const int k0 = kk * 32;
    __syncthreads();
#pragma unroll
    for (int q = 0; q < 2; ++q) {
      int idx = q * 256 + tid;
      int row = idx >> 2, c = idx & 3;
      gload_lds16(A  + (brow + row) * 512 + k0 + c * 8, &lA[idx * 8]);
      gload_lds16(Bw + (size_t)(bcol + row) * 512 + k0 + c * 8, &lB[idx * 8]);
    }
    __syncthreads();

    bf16x8 af[4], bfr[4];
#pragma unroll
    for (int m = 0; m < 4; ++m) {
      int row = wr * 64 + m * 16 + (lane & 15);
      af[m] = ld8(&lA[row * 32 + (lane >> 4) * 8]);
    }
#pragma unroll
    for (int n = 0; n < 4; ++n) {
      int row = wc * 64 + n * 16 + (lane & 15);
      bfr[n] = ld8(&lB[row * 32 + (lane >> 4) * 8]);
    }
#pragma unroll
    for (int m = 0; m < 4; ++m)
#pragma unroll
      for (int n = 0; n < 4; ++n)
        acc[m][n] = __builtin_amdgcn_mfma_f32_16x16x32_bf16(af[m], bfr[n], acc[m][n], 0, 0, 0);
  }

#pragma unroll
  for (int m = 0; m < 4; ++m) {
#pragma unroll
    for (int n = 0; n < 4; ++n) {
      int col = bcol + wc * 64 + n * 16 + (lane & 15);
      float bb = bias[col];
#pragma unroll
      for (int r = 0; r < 4; ++r) {
        size_t row = brow + wr * 64 + m * 16 + (lane >> 4) * 4 + r;
        float v = acc[m][n][r] + bb;
        if (XGBF16) Ch[row * 4096 + col] = f2bf(v);
        else        Cf[row * 4096 + col] = v;
      }
    }
  }
}

// ---------- phase 2: persistent recurrence, tag-in-data exchange ----------
// 32 blocks: d = bid>>4, ntile = bid&15 (128 gate-cols per block).
// Each published u64 slot = {lo: packed 2xbf16 h, hi: step tag}. 8B stores are
// single-copy atomic -> tag visible implies data visible: no producer drain,
// no flag, no post-publish sync. Consumers poll their own 32 slots (batched
// loads, single-producer per thread) until all tags == t, then stage to LDS.
// Safety: block publishes t+1 only after consuming tags==t from all producers
// (via the staging barrier), so buf[(t+1)&1]'s previous readers are done; tags
// strictly increase -> no ABA. Slot: [pp][dir][b 0..31][blk 0..15][jp 0..15].
template <bool XGBF16>
__global__ __launch_bounds__(256, 1) void k_rnn(
    const u16* __restrict__ whp,
    const float* __restrict__ xgf, const u16* __restrict__ xgh,
    u64* __restrict__ hbuf,
    float* __restrict__ out, float* __restrict__ fh, float* __restrict__ fc) {
  const int tid  = threadIdx.x;
  const int lane = tid & 63;
  const int w    = tid >> 6;
  const int bid  = (int)blockIdx.x;
  const int d     = bid >> 4;
  const int ntile = bid & 15;

  __shared__ __align__(16) u16 hlds[32 * 512];      // 32KB staged h (swizzled)
  __shared__ __align__(16) float gbuf[32][132];     // padded repartition buffer

  // ---- Wh slice -> registers (once; r7-identical) ----
  const u16* wbase = whp + (size_t)(d * 2048 + ntile * 128 + w * 32) * 512;
  const int r0 = lane & 15;
  const int qb = lane >> 4;
  bf16x8 wf[16][2];
#pragma unroll
  for (int kk = 0; kk < 16; ++kk)
#pragma unroll
    for (int n = 0; n < 2; ++n)
      wf[kk][n] = ld8(wbase + (size_t)(n * 16 + r0) * 512 + kk * 32 + qb * 8);

  const int brow = tid >> 4;        // 0..15 (also my staged producer blk)
  const int jp   = tid & 15;
  const int colbase = d * 2048 + ntile * 128 + jp * 8;
  const int swz = r0 & 7;

  // staging address components (consumer): slot r*256+tid covers
  // (b=r, blk=tid>>4, jp=tid&15) -> row r, 16B-unit c16 = blk*4 + (jp>>2)
  const int c16 = (tid >> 4) * 4 + ((tid >> 2) & 3);
  const int o4  = (tid & 3) * 4;

  float cst[2][2] = {{0.f, 0.f}, {0.f, 0.f}};

  for (int t = 0; t < 1024; ++t) {
    const int sd = d ? (1023 - t) : t;

    // ---- xg prefetch (cached; overlaps the poll) ----
    short8v xh0, xh1;
    f32x4 xf0a, xf0b, xf1a, xf1b;
    {
      size_t xoff0 = ((size_t)(brow * 1024 + sd)) * 4096 + colbase;
      size_t xoff1 = ((size_t)((16 + brow) * 1024 + sd)) * 4096 + colbase;
      if (XGBF16) {
        xh0 = *reinterpret_cast<const short8v*>(xgh + xoff0);
        xh1 = *reinterpret_cast<const short8v*>(xgh + xoff1);
      } else {
        xf0a = *reinterpret_cast<const f32x4*>(xgf + xoff0);
        xf0b = *reinterpret_cast<const f32x4*>(xgf + xoff0 + 4);
        xf1a = *reinterpret_cast<const f32x4*>(xgf + xoff1);
        xf1b = *reinterpret_cast<const f32x4*>(xgf + xoff1 + 4);
      }
    }

    // ---- poll own 32 tagged slots (batched; 1 LLC RT per round) ----
    const u64* hb = hbuf + ((size_t)(t & 1) * 2 + d) * 8192;
    u64 hv[32];
    for (;;) {
#pragma unroll
      for (int r = 0; r < 32; ++r)
        hv[r] = __hip_atomic_load(hb + r * 256 + tid,
                                  __ATOMIC_RELAXED, __HIP_MEMORY_SCOPE_AGENT);
      u32 bad = 0;
#pragma unroll
      for (int r = 0; r < 32; ++r)
        bad |= ((u32)(hv[r] >> 32)) ^ (u32)t;
      if (!bad) break;
      __builtin_amdgcn_s_sleep(1);
    }
    asm volatile("" ::: "memory");

    // ---- stage h pairs to LDS (swizzled; 2-way bank aliased = free) ----
    {
      char* hby = (char*)hlds;
#pragma unroll
      for (int r = 0; r < 32; ++r)
        *(u32*)(hby + r * 1024 + (size_t)((c16 ^ (r & 7)) << 4) + o4) = (u32)hv[r];
    }
    __syncthreads();

    // ---- g = h @ Wh_slice^T (MFMA; r7-identical) ----
    f32x4 acc[2][2] = {};
    {
      const char* hbc = (const char*)hlds;
#pragma unroll
      for (int kk = 0; kk < 16; ++kk) {
        int u0 = (((kk * 4 + qb) ^ swz) << 4);
        bf16x8 a0 = *(const bf16x8*)(hbc + r0 * 1024 + u0);
        bf16x8 a1 = *(const bf16x8*)(hbc + (16 + r0) * 1024 + u0);
#pragma unroll
        for (int n = 0; n < 2; ++n) {
          acc[0][n] = __builtin_amdgcn_mfma_f32_16x16x32_bf16(a0, wf[kk][n], acc[0][n], 0, 0, 0);
          acc[1][n] = __builtin_amdgcn_mfma_f32_16x16x32_bf16(a1, wf[kk][n], acc[1][n], 0, 0, 0);
        }
      }
    }

    // ---- stage g to LDS for gate repartition ----
#pragma unroll
    for (int m = 0; m < 2; ++m)
#pragma unroll
      for (int n = 0; n < 2; ++n)
#pragma unroll
        for (int r = 0; r < 4; ++r)
          gbuf[m * 16 + qb * 4 + r][w * 32 + n * 16 + r0] = acc[m][n][r];
    __syncthreads();

    // ---- gates + cell update ----
    u32 pk[2];
    float hh[2][2];
#pragma unroll
    for (int it = 0; it < 2; ++it) {
      int b = it * 16 + brow;
      float4 g0 = *reinterpret_cast<const float4*>(&gbuf[b][jp * 8]);
      float4 g1 = *reinterpret_cast<const float4*>(&gbuf[b][jp * 8 + 4]);
      float xi0, xff0, xo0, xc0, xi1, xff1, xo1, xc1;
      if (XGBF16) {
        const short8v& xv = it ? xh1 : xh0;
        xi0 = bf2f((u16)xv[0]); xff0 = bf2f((u16)xv[1]);
        xo0 = bf2f((u16)xv[2]); xc0  = bf2f((u16)xv[3]);
        xi1 = bf2f((u16)xv[4]); xff1 = bf2f((u16)xv[5]);
        xo1 = bf2f((u16)xv[6]); xc1  = bf2f((u16)xv[7]);
      } else {
        const f32x4& va = it ? xf1a : xf0a;
        const f32x4& vb = it ? xf1b : xf0b;
        xi0 = va[0]; xff0 = va[1]; xo0 = va[2]; xc0 = va[3];
        xi1 = vb[0]; xff1 = vb[1]; xo1 = vb[2]; xc1 = vb[3];
      }
      float gi0 = g0.x + xi0, gf0 = g0.y + xff0, go0 = g0.z + xo0, gc0 = g0.w + xc0;
      float gi1 = g1.x + xi1, gf1 = g1.y + xff1, go1 = g1.z + xo1, gc1 = g1.w + xc1;
      float cn0 = sigf(gf0) * cst[it][0] + sigf(gi0) * tanhfast(gc0);
      float cn1 = sigf(gf1) * cst[it][1] + sigf(gi1) * tanhfast(gc1);
      float hn0 = sigf(go0) * tanhfast(cn0);
      float hn1 = sigf(go1) * tanhfast(cn1);
      cst[it][0] = cn0; cst[it][1] = cn1;
      pk[it] = (u32)f2bf(hn0) | ((u32)f2bf(hn1) << 16);
      hh[it][0] = hn0; hh[it][1] = hn1;
    }

    // ---- publish tagged h (fire-and-forget: no drain, no flag, no sync) ----
    if (t < 1023) {
      u64* hd = hbuf + ((size_t)((t + 1) & 1) * 2 + d) * 8192;
      const u64 tag = ((u64)(u32)(t + 1)) << 32;
#pragma unroll
      for (int it = 0; it < 2; ++it) {
        int b = it * 16 + brow;
        __hip_atomic_store(hd + b * 256 + ntile * 16 + jp, (u64)pk[it] | tag,
                           __ATOMIC_RELAXED, __HIP_MEMORY_SCOPE_AGENT);
      }
    }

    // ---- out / final stores (coalesced NT) ----
#pragma unroll
    for (int it = 0; it < 2; ++it) {
      int b = it * 16 + brow;
      f32x2 ov; ov.x = hh[it][0]; ov.y = hh[it][1];
      __builtin_nontemporal_store(ov, reinterpret_cast<f32x2*>(
          out + ((size_t)(b * 1024 + sd)) * 1024 + d * 512 + ntile * 32 + jp * 2));
      if (t == 1023) {
        int fo = b * 1024 + d * 512 + ntile * 32 + jp * 2;
        f32x2 hv2; hv2.x = hh[it][0]; hv2.y = hh[it][1];
        f32x2 cv2; cv2.x = cst[it][0]; cv2.y = cst[it][1];
        *reinterpret_cast<f32x2*>(fh + fo) = hv2;
        *reinterpret_cast<f32x2*>(fc + fo) = cv2;
      }
    }
  }
}

// ---------- host ----------
extern "C" void kernel_launch(void* const* d_in, const int* in_sizes, int n_in,
                              void* d_out, int out_size, void* d_ws, size_t ws_size,
                              hipStream_t stream) {
  (void)in_sizes; (void)n_in; (void)out_size;
  const float* x    = (const float*)d_in[0];
  const float* Wx_f = (const float*)d_in[1];
  const float* Wh_f = (const float*)d_in[2];
  const float* bx_f = (const float*)d_in[3];
  const float* bh_f = (const float*)d_in[4];
  const float* Wx_b = (const float*)d_in[5];
  const float* Wh_b = (const float*)d_in[6];
  const float* bx_b = (const float*)d_in[7];
  const float* bh_b = (const float*)d_in[8];

  char* ws = (char*)d_ws;
  const size_t XG_F32 = (size_t)32768 * 4096 * 4;   // 512 MB
  const size_t XG_BF  = (size_t)32768 * 4096 * 2;   // 256 MB
  const size_t REST   = 33554432 + 4194304 + 4194304 + 16384 + 262144;
  const bool xg_bf16 = (ws_size < XG_F32 + REST);

  size_t off = xg_bf16 ? XG_BF : XG_F32;
  float* xg_f = (float*)ws;
  u16*   xg_h = (u16*)ws;
  u16*   xh   = (u16*)(ws + off);  off += 33554432;   // x as bf16
  u16*   wall = (u16*)(ws + off);  off += 4194304;    // packed Wx (both dirs)
  u16*   whp  = (u16*)(ws + off);  off += 4194304;    // packed Wh (both dirs)
  float* bias = (float*)(ws + off); off += 16384;     // bx+bh packed
  u64*   hbuf = (u64*)(ws + off);  off += 262144;     // [2pp][2dir][32b][16blk][16jp] u64

  float* out = (float*)d_out;
  float* fh  = out + (size_t)33554432;
  float* fc  = fh + 32768;

  hipError_t e = hipMemsetAsync(hbuf, 0, 262144, stream); // h slots (tag 0 = step 0 valid)
  (void)e;
  k_conv_x<<<16384, 256, 0, stream>>>(x, xh);
  k_pack_w<<<2048, 256, 0, stream>>>(Wx_f, Wh_f, bx_f, bh_f,
                                     Wx_b, Wh_b, bx_b, bh_b, wall, whp, bias);
  if (xg_bf16) {
    k_gemm_xg<true><<<dim3(32, 256), 256, 0, stream>>>(xh, wall, bias, nullptr, xg_h);
    k_rnn<true><<<32, 256, 0, stream>>>(whp, nullptr, xg_h, hbuf, out, fh, fc);
  } else {
    k_gemm_xg<false><<<dim3(32, 256), 256, 0, stream>>>(xh, wall, bias, xg_f, nullptr);
    k_rnn<false><<<32, 256, 0, stream>>>(whp, xg_f, nullptr, hbuf, out, fh, fc);
  }
}

// Round 13
// 3822.739 us; speedup vs baseline: 1.4995x; 1.1231x over previous
//
#include <hip/hip_runtime.h>

typedef unsigned short u16;
typedef unsigned int u32;
typedef unsigned long long u64;
typedef __attribute__((ext_vector_type(8))) short short8v;
typedef __attribute__((ext_vector_type(8))) __bf16 bf16x8;
typedef __attribute__((ext_vector_type(4))) float f32x4;
typedef __attribute__((ext_vector_type(2))) float f32x2;

#define AS1 __attribute__((address_space(1)))
#define AS3 __attribute__((address_space(3)))

// ---------- helpers ----------
__device__ __forceinline__ u16 f2bf(float f) {
  unsigned u = __float_as_uint(f);
  u += 0x7fffu + ((u >> 16) & 1u);   // round-to-nearest-even
  return (u16)(u >> 16);
}
__device__ __forceinline__ float bf2f(u16 h) {
  return __uint_as_float(((unsigned)h) << 16);
}
__device__ __forceinline__ void gload_lds16(const void* g, void* l) {
  __builtin_amdgcn_global_load_lds((const AS1 void*)g, (AS3 void*)l, 16, 0, 0);
}
__device__ __forceinline__ bf16x8 ld8(const u16* p) {
  return __builtin_bit_cast(bf16x8, *reinterpret_cast<const short8v*>(p));
}
__device__ __forceinline__ float sigf(float x) { return 1.0f / (1.0f + __expf(-x)); }
__device__ __forceinline__ float tanhfast(float x) {
  float e = __expf(2.0f * x);
  return 1.0f - 2.0f / (e + 1.0f);
}

// ---------- setup kernels ----------
__global__ __launch_bounds__(256) void k_conv_x(const float* __restrict__ x,
                                                u16* __restrict__ xh) {
  int i = blockIdx.x * 256 + threadIdx.x;
  float4 v = reinterpret_cast<const float4*>(x)[i];
  ushort4 o;
  o.x = f2bf(v.x); o.y = f2bf(v.y); o.z = f2bf(v.z); o.w = f2bf(v.w);
  reinterpret_cast<ushort4*>(xh)[i] = o;
}

// gate-interleaved packing: n' = d*2048 + 4j + g, src row = g*512 + j
__global__ __launch_bounds__(256) void k_pack_w(
    const float* __restrict__ Wx_f, const float* __restrict__ Wh_f,
    const float* __restrict__ bx_f, const float* __restrict__ bh_f,
    const float* __restrict__ Wx_b, const float* __restrict__ Wh_b,
    const float* __restrict__ bx_b, const float* __restrict__ bh_b,
    u16* __restrict__ wall, u16* __restrict__ whp, float* __restrict__ bias) {
  int i = blockIdx.x * 256 + threadIdx.x;
  int np = i >> 7;
  int k4 = i & 127;
  int d  = np >> 11;
  int p  = np & 2047;
  int src = (p & 3) * 512 + (p >> 2);
  const float* wx = d ? Wx_b : Wx_f;
  const float* wh = d ? Wh_b : Wh_f;
  float4 vx = reinterpret_cast<const float4*>(wx + (size_t)src * 512)[k4];
  float4 vh = reinterpret_cast<const float4*>(wh + (size_t)src * 512)[k4];
  ushort4 ox, oh;
  ox.x = f2bf(vx.x); ox.y = f2bf(vx.y); ox.z = f2bf(vx.z); ox.w = f2bf(vx.w);
  oh.x = f2bf(vh.x); oh.y = f2bf(vh.y); oh.z = f2bf(vh.z); oh.w = f2bf(vh.w);
  reinterpret_cast<ushort4*>(wall + (size_t)np * 512)[k4] = ox;
  reinterpret_cast<ushort4*>(whp  + (size_t)np * 512)[k4] = oh;
  if (k4 == 0) bias[np] = d ? (bx_b[src] + bh_b[src]) : (bx_f[src] + bh_f[src]);
}

// ---------- phase 1: xg = xh @ wall^T + bias ----------
template <bool XGBF16>
__global__ __launch_bounds__(256) void k_gemm_xg(
    const u16* __restrict__ A, const u16* __restrict__ Bw,
    const float* __restrict__ bias,
    float* __restrict__ Cf, u16* __restrict__ Ch) {
  __shared__ __align__(16) u16 lA[128 * 32];
  __shared__ __align__(16) u16 lB[128 * 32];
  const int tid  = threadIdx.x;
  const int lane = tid & 63;
  const int w    = tid >> 6;
  const int wr   = w >> 1, wc = w & 1;
  const size_t brow = (size_t)blockIdx.y * 128;
  const int    bcol = blockIdx.x * 128;

  f32x4 acc[4][4] = {};

  for (int kk = 0; kk < 16; ++kk) {
    const int k0 = kk * 32;
    __syncthreads();
#pragma unroll
    for (int q = 0; q < 2; ++q) {
      int idx = q * 256 + tid;
      int row = idx >> 2, c = idx & 3;
      gload_lds16(A  + (brow + row) * 512 + k0 + c * 8, &lA[idx * 8]);
      gload_lds16(Bw + (size_t)(bcol + row) * 512 + k0 + c * 8, &lB[idx * 8]);
    }
    __syncthreads();

    bf16x8 af[4], bfr[4];
#pragma unroll
    for (int m = 0; m < 4; ++m) {
      int row = wr * 64 + m * 16 + (lane & 15);
      af[m] = ld8(&lA[row * 32 + (lane >> 4) * 8]);
    }
#pragma unroll
    for (int n = 0; n < 4; ++n) {
      int row = wc * 64 + n * 16 + (lane & 15);
      bfr[n] = ld8(&lB[row * 32 + (lane >> 4) * 8]);
    }
#pragma unroll
    for (int m = 0; m < 4; ++m)
#pragma unroll
      for (int n = 0; n < 4; ++n)
        acc[m][n] = __builtin_amdgcn_mfma_f32_16x16x32_bf16(af[m], bfr[n], acc[m][n], 0, 0, 0);
  }

#pragma unroll
  for (int m = 0; m < 4; ++m) {
#pragma unroll
    for (int n = 0; n < 4; ++n) {
      int col = bcol + wc * 64 + n * 16 + (lane & 15);
      float bb = bias[col];
#pragma unroll
      for (int r = 0; r < 4; ++r) {
        size_t row = brow + wr * 64 + m * 16 + (lane >> 4) * 4 + r;
        float v = acc[m][n][r] + bb;
        if (XGBF16) Ch[row * 4096 + col] = f2bf(v);
        else        Cf[row * 4096 + col] = v;
      }
    }
  }
}

// ---------- phase 2: persistent recurrence (r7 structure + pinned Wh) ----------
// 32 blocks: d = bid>>4, ntile = bid&15 (128 gate-cols per block).
// SINGLE delta vs r7: Wh fragments are pinned into VGPRs via an opaque asm
// (compiler cannot rematerialize/sink the loads), eliminating the 128 KB/step
// per-block L2 weight re-stream that r7's VGPR_Count=124 revealed.
template <bool XGBF16>
__global__ __launch_bounds__(256, 1) void k_rnn(
    const u16* __restrict__ whp,
    const float* __restrict__ xgf, const u16* __restrict__ xgh,
    u32* __restrict__ hbuf, u32* __restrict__ flags,
    float* __restrict__ out, float* __restrict__ fh, float* __restrict__ fc) {
  const int tid  = threadIdx.x;
  const int lane = tid & 63;
  const int w    = tid >> 6;
  const int bid  = (int)blockIdx.x;
  const int d     = bid >> 4;
  const int ntile = bid & 15;

  __shared__ __align__(16) u16 hlds[32 * 512];      // 32KB staged h (swizzled)
  __shared__ __align__(16) float gbuf[32][132];     // padded repartition buffer

  // ---- Wh slice -> registers (once), PINNED resident ----
  const u16* wbase = whp + (size_t)(d * 2048 + ntile * 128 + w * 32) * 512;
  bf16x8 wf[16][2];
#pragma unroll
  for (int kk = 0; kk < 16; ++kk)
#pragma unroll
    for (int n = 0; n < 2; ++n)
      wf[kk][n] = ld8(wbase + (size_t)(n * 16 + (lane & 15)) * 512 + kk * 32 + (lane >> 4) * 8);
#pragma unroll
  for (int kk = 0; kk < 16; ++kk)
#pragma unroll
    for (int n = 0; n < 2; ++n) {
      f32x4 tpin = __builtin_bit_cast(f32x4, wf[kk][n]);
      asm volatile("" : "+v"(tpin));                 // opaque: forces residency
      wf[kk][n] = __builtin_bit_cast(bf16x8, tpin);
    }

  const int brow = tid >> 4;        // 0..15
  const int jp   = tid & 15;
  const int colbase = d * 2048 + ntile * 128 + jp * 8;
  const int r0 = lane & 15;
  const int qb = lane >> 4;
  const int swz = r0 & 7;

  float cst[2][2] = {{0.f, 0.f}, {0.f, 0.f}};

  const int FSTR = 64;                               // 256 B between flags
  u32* myflag = flags + (d * 16 + ntile) * FSTR;
  // producer of the h-slice this thread stages: u64-col = tid&127 -> slice (tid&127)>>3
  const u32* spinflag = flags + (d * 16 + ((tid & 127) >> 3)) * FSTR;

  for (int t = 0; t < 1024; ++t) {
    const int sd = d ? (1023 - t) : t;

    // ---- xg prefetch (regular cached loads; overlaps the spin) ----
    short8v xh0, xh1;
    f32x4 xf0a, xf0b, xf1a, xf1b;
    {
      size_t xoff0 = ((size_t)(brow * 1024 + sd)) * 4096 + colbase;
      size_t xoff1 = ((size_t)((16 + brow) * 1024 + sd)) * 4096 + colbase;
      if (XGBF16) {
        xh0 = *reinterpret_cast<const short8v*>(xgh + xoff0);
        xh1 = *reinterpret_cast<const short8v*>(xgh + xoff1);
      } else {
        xf0a = *reinterpret_cast<const f32x4*>(xgf + xoff0);
        xf0b = *reinterpret_cast<const f32x4*>(xgf + xoff0 + 4);
        xf1a = *reinterpret_cast<const f32x4*>(xgf + xoff1);
        xf1b = *reinterpret_cast<const f32x4*>(xgf + xoff1 + 4);
      }
    }

    // ---- wait for the producer of the h-slice this thread stages ----
    if (t > 0) {
      while (__hip_atomic_load(spinflag, __ATOMIC_RELAXED, __HIP_MEMORY_SCOPE_AGENT) < (u32)t)
        __builtin_amdgcn_s_sleep(1);
      asm volatile("" ::: "memory");
    }

    // ---- load h (16 x u64 per thread, LLC-coherent) ----
    const u64* hg = (const u64*)hbuf + ((size_t)(t & 1) * 2 + d) * 4096;
    u64 hv[16];
#pragma unroll
    for (int p = 0; p < 16; ++p)
      hv[p] = __hip_atomic_load(hg + p * 256 + tid, __ATOMIC_RELAXED, __HIP_MEMORY_SCOPE_AGENT);

    // ---- stage h to LDS: row b, 16B unit u stored at u^(b&7) ----
    {
      char* hb = (char*)hlds;
#pragma unroll
      for (int p = 0; p < 16; ++p) {
        int idx = p * 256 + tid;
        int b = idx >> 7, jq = idx & 127;
        *(u64*)(hb + b * 1024 + (((jq >> 1) ^ (b & 7)) << 4) + ((jq & 1) << 3)) = hv[p];
      }
    }
    __syncthreads();

    // ---- g = h @ Wh_slice^T (MFMA) ----
    f32x4 acc[2][2] = {};
    {
      const char* hbc = (const char*)hlds;
#pragma unroll
      for (int kk = 0; kk < 16; ++kk) {
        int u0 = (((kk * 4 + qb) ^ swz) << 4);
        bf16x8 a0 = *(const bf16x8*)(hbc + r0 * 1024 + u0);
        bf16x8 a1 = *(const bf16x8*)(hbc + (16 + r0) * 1024 + u0);
#pragma unroll
        for (int n = 0; n < 2; ++n) {
          acc[0][n] = __builtin_amdgcn_mfma_f32_16x16x32_bf16(a0, wf[kk][n], acc[0][n], 0, 0, 0);
          acc[1][n] = __builtin_amdgcn_mfma_f32_16x16x32_bf16(a1, wf[kk][n], acc[1][n], 0, 0, 0);
        }
      }
    }

    // ---- stage g to LDS for gate repartition ----
#pragma unroll
    for (int m = 0; m < 2; ++m)
#pragma unroll
      for (int n = 0; n < 2; ++n)
#pragma unroll
        for (int r = 0; r < 4; ++r)
          gbuf[m * 16 + qb * 4 + r][w * 32 + n * 16 + r0] = acc[m][n][r];
    __syncthreads();

    // ---- gates + cell update (values kept in registers) ----
    u32* hdst = hbuf + ((size_t)((t + 1) & 1) * 2 + d) * 8192;
    u32 pk[2];
    float hh[2][2];
#pragma unroll
    for (int it = 0; it < 2; ++it) {
      int b = it * 16 + brow;
      float4 g0 = *reinterpret_cast<const float4*>(&gbuf[b][jp * 8]);
      float4 g1 = *reinterpret_cast<const float4*>(&gbuf[b][jp * 8 + 4]);
      float xi0, xff0, xo0, xc0, xi1, xff1, xo1, xc1;
      if (XGBF16) {
        const short8v& xv = it ? xh1 : xh0;
        xi0 = bf2f((u16)xv[0]); xff0 = bf2f((u16)xv[1]);
        xo0 = bf2f((u16)xv[2]); xc0  = bf2f((u16)xv[3]);
        xi1 = bf2f((u16)xv[4]); xff1 = bf2f((u16)xv[5]);
        xo1 = bf2f((u16)xv[6]); xc1  = bf2f((u16)xv[7]);
      } else {
        const f32x4& va = it ? xf1a : xf0a;
        const f32x4& vb = it ? xf1b : xf0b;
        xi0 = va[0]; xff0 = va[1]; xo0 = va[2]; xc0 = va[3];
        xi1 = vb[0]; xff1 = vb[1]; xo1 = vb[2]; xc1 = vb[3];
      }
      float gi0 = g0.x + xi0, gf0 = g0.y + xff0, go0 = g0.z + xo0, gc0 = g0.w + xc0;
      float gi1 = g1.x + xi1, gf1 = g1.y + xff1, go1 = g1.z + xo1, gc1 = g1.w + xc1;
      float cn0 = sigf(gf0) * cst[it][0] + sigf(gi0) * tanhfast(gc0);
      float cn1 = sigf(gf1) * cst[it][1] + sigf(gi1) * tanhfast(gc1);
      float hn0 = sigf(go0) * tanhfast(cn0);
      float hn1 = sigf(go1) * tanhfast(cn1);
      cst[it][0] = cn0; cst[it][1] = cn1;
      pk[it] = (u32)f2bf(hn0) | ((u32)f2bf(hn1) << 16);
      hh[it][0] = hn0; hh[it][1] = hn1;
    }

    // ---- publish h, drain, flag ----
#pragma unroll
    for (int it = 0; it < 2; ++it) {
      int b = it * 16 + brow;
      __hip_atomic_store(hdst + b * 256 + ntile * 16 + jp, pk[it],
                         __ATOMIC_RELAXED, __HIP_MEMORY_SCOPE_AGENT);
    }
    asm volatile("s_waitcnt vmcnt(0)" ::: "memory");
    __syncthreads();
    if (tid == 0)
      __hip_atomic_store(myflag, (u32)(t + 1), __ATOMIC_RELAXED, __HIP_MEMORY_SCOPE_AGENT);

    // ---- out / final stores (off the critical path, coalesced) ----
#pragma unroll
    for (int it = 0; it < 2; ++it) {
      int b = it * 16 + brow;
      f32x2 ov; ov.x = hh[it][0]; ov.y = hh[it][1];
      __builtin_nontemporal_store(ov, reinterpret_cast<f32x2*>(
          out + ((size_t)(b * 1024 + sd)) * 1024 + d * 512 + ntile * 32 + jp * 2));
      if (t == 1023) {
        int fo = b * 1024 + d * 512 + ntile * 32 + jp * 2;
        f32x2 hv2; hv2.x = hh[it][0]; hv2.y = hh[it][1];
        f32x2 cv2; cv2.x = cst[it][0]; cv2.y = cst[it][1];
        *reinterpret_cast<f32x2*>(fh + fo) = hv2;
        *reinterpret_cast<f32x2*>(fc + fo) = cv2;
      }
    }
  }
}

// ---------- host ----------
extern "C" void kernel_launch(void* const* d_in, const int* in_sizes, int n_in,
                              void* d_out, int out_size, void* d_ws, size_t ws_size,
                              hipStream_t stream) {
  (void)in_sizes; (void)n_in; (void)out_size;
  const float* x    = (const float*)d_in[0];
  const float* Wx_f = (const float*)d_in[1];
  const float* Wh_f = (const float*)d_in[2];
  const float* bx_f = (const float*)d_in[3];
  const float* bh_f = (const float*)d_in[4];
  const float* Wx_b = (const float*)d_in[5];
  const float* Wh_b = (const float*)d_in[6];
  const float* bx_b = (const float*)d_in[7];
  const float* bh_b = (const float*)d_in[8];

  char* ws = (char*)d_ws;
  const size_t XG_F32 = (size_t)32768 * 4096 * 4;   // 512 MB
  const size_t XG_BF  = (size_t)32768 * 4096 * 2;   // 256 MB
  const size_t REST   = 33554432 + 4194304 + 4194304 + 16384 + 262144 + 16384;
  const bool xg_bf16 = (ws_size < XG_F32 + REST);

  size_t off = xg_bf16 ? XG_BF : XG_F32;
  float* xg_f = (float*)ws;
  u16*   xg_h = (u16*)ws;
  u16*   xh   = (u16*)(ws + off);  off += 33554432;   // x as bf16
  u16*   wall = (u16*)(ws + off);  off += 4194304;    // packed Wx (both dirs)
  u16*   whp  = (u16*)(ws + off);  off += 4194304;    // packed Wh (both dirs)
  float* bias = (float*)(ws + off); off += 16384;     // bx+bh packed
  u32*   hbuf = (u32*)(ws + off);  off += 262144;     // [2 pp][2 dir][32][256] u32
  u32*   flags = (u32*)(ws + off); off += 16384;      // 32 flags, 256 B apart

  float* out = (float*)d_out;
  float* fh  = out + (size_t)33554432;
  float* fc  = fh + 32768;

  hipError_t e = hipMemsetAsync(hbuf, 0, 262144 + 16384, stream); // h state + flags
  (void)e;
  k_conv_x<<<16384, 256, 0, stream>>>(x, xh);
  k_pack_w<<<2048, 256, 0, stream>>>(Wx_f, Wh_f, bx_f, bh_f,
                                     Wx_b, Wh_b, bx_b, bh_b, wall, whp, bias);
  if (xg_bf16) {
    k_gemm_xg<true><<<dim3(32, 256), 256, 0, stream>>>(xh, wall, bias, nullptr, xg_h);
    k_rnn<true><<<32, 256, 0, stream>>>(whp, nullptr, xg_h, hbuf, flags, out, fh, fc);
  } else {
    k_gemm_xg<false><<<dim3(32, 256), 256, 0, stream>>>(xh, wall, bias, xg_f, nullptr);
    k_rnn<false><<<32, 256, 0, stream>>>(whp, xg_f, nullptr, hbuf, flags, out, fh, fc);
  }
}